// Round 2
// baseline (1284.162 us; speedup 1.0000x reference)
//
#include <hip/hip_runtime.h>
#include <hip/hip_bf16.h>

typedef unsigned short u16;
typedef __bf16 bf16x8 __attribute__((ext_vector_type(8)));
typedef float  f32x4  __attribute__((ext_vector_type(4)));

#define B_   4
#define S_   4096
#define D_   2048
#define C_   64
#define T_   (B_*S_)      // 16384 tokens
#define NALL 6144         // 3*D (q,k,v)
#define NCH  16           // token chunks per batch for scatter

__device__ __forceinline__ u16 f2bf(float f) {
  union { float f; unsigned u; } c; c.f = f;
  unsigned r = c.u + 0x7FFFu + ((c.u >> 16) & 1u);
  return (u16)(r >> 16);
}
__device__ __forceinline__ float bf2f(u16 u) {
  union { float f; unsigned u; } c; c.u = ((unsigned)u) << 16;
  return c.f;
}

__device__ __forceinline__ void gload16(const u16* g, u16* l) {
  __builtin_amdgcn_global_load_lds(
      (__attribute__((address_space(1))) void*)(void*)g,
      (__attribute__((address_space(3))) void*)l, 16, 0, 0);
}

// ---------------- generic 128x128 bt-GEMM (A [M,K] bf16, BT [N,K] bf16) ----------------
// EPI 0: fused qkv epilogue (qnorm2/knorm2 atomics, v bf16 store; all *mask)
// EPI 2: +bias, write bf16 (ch_out)
// EPI 3: write fp32 (chproj)
template<int EPI>
__global__ __launch_bounds__(256)
void gemm_bt(const u16* __restrict__ A, const u16* __restrict__ BT, int K,
             const float* __restrict__ mask,
             float* __restrict__ qn2, float* __restrict__ kn2,
             u16* __restrict__ uout, float* __restrict__ fout,
             const float* __restrict__ bias)
{
  __shared__ u16 lA[128 * 32];
  __shared__ u16 lB[128 * 32];
  const int bm = blockIdx.x, bn = blockIdx.y;
  const int tid = threadIdx.x;
  const int wid = tid >> 6, lane = tid & 63;
  const int wm = wid >> 1, wn = wid & 1;
  const int lcol = lane & 15, khalf = lane >> 4;
  const int kb = khalf * 8;

  f32x4 acc[4][4] = {};

  const u16* Ab = A + (size_t)bm * 128 * K;
  const u16* Bb = BT + (size_t)bn * 128 * K;
  const int arow = wm * 64 + lcol;
  const int brow = wn * 64 + lcol;

  for (int kt = 0; kt < K; kt += 32) {
#pragma unroll
    for (int i = 0; i < 2; ++i) {
      int idx = tid + i * 256;
      int r = idx >> 2, ko = (idx & 3) << 3;
      gload16(Ab + (size_t)r * K + kt + ko, &lA[idx * 8]);
      gload16(Bb + (size_t)r * K + kt + ko, &lB[idx * 8]);
    }
    __syncthreads();
    bf16x8 av[4], bv[4];
#pragma unroll
    for (int f = 0; f < 4; ++f) {
      av[f] = *(const bf16x8*)&lA[(arow + f * 16) * 32 + kb];
      bv[f] = *(const bf16x8*)&lB[(brow + f * 16) * 32 + kb];
    }
#pragma unroll
    for (int m = 0; m < 4; ++m)
#pragma unroll
      for (int n = 0; n < 4; ++n)
        acc[m][n] = __builtin_amdgcn_mfma_f32_16x16x32_bf16(av[m], bv[n], acc[m][n], 0, 0, 0);
    __syncthreads();
  }

  const int r0 = bm * 128 + wm * 64;
  const int c0 = bn * 128 + wn * 64;
  const int lrow = khalf * 4;

  if constexpr (EPI == 0) {
    const int region = bn >> 4;  // 0:q 1:k 2:v
#pragma unroll
    for (int fm = 0; fm < 4; ++fm) {
#pragma unroll
      for (int i = 0; i < 4; ++i) {
        int row = r0 + fm * 16 + lrow + i;
        float mv = mask[row];
        if (region < 2) {
          float ss = 0.f;
#pragma unroll
          for (int fn = 0; fn < 4; ++fn) { float v = acc[fm][fn][i] * mv; ss += v * v; }
#pragma unroll
          for (int d = 1; d < 16; d <<= 1) ss += __shfl_xor(ss, d);
          if (lcol == 0) atomicAdd((region == 0 ? qn2 : kn2) + row, ss);
        } else {
#pragma unroll
          for (int fn = 0; fn < 4; ++fn) {
            int col = c0 + fn * 16 + lcol - 4096;
            uout[(size_t)row * D_ + col] = f2bf(acc[fm][fn][i] * mv);
          }
        }
      }
    }
  } else if constexpr (EPI == 2) {
#pragma unroll
    for (int fm = 0; fm < 4; ++fm)
#pragma unroll
      for (int i = 0; i < 4; ++i) {
        int row = r0 + fm * 16 + lrow + i;
#pragma unroll
        for (int fn = 0; fn < 4; ++fn) {
          int col = c0 + fn * 16 + lcol;
          uout[(size_t)row * D_ + col] = f2bf(acc[fm][fn][i] + bias[col]);
        }
      }
  } else {
#pragma unroll
    for (int fm = 0; fm < 4; ++fm)
#pragma unroll
      for (int i = 0; i < 4; ++i) {
        int row = r0 + fm * 16 + lrow + i;
#pragma unroll
        for (int fn = 0; fn < 4; ++fn) {
          int col = c0 + fn * 16 + lcol;
          fout[(size_t)row * D_ + col] = acc[fm][fn][i];
        }
      }
  }
}

// ---------------- split-precision GEMM: out = (Ah+Al) @ (Bh+Bl)^T, fp32 out ----------------
// tile 128 rows x 64 cols, all 4 cross terms -> fp32-accurate result
__global__ __launch_bounds__(256)
void gemm4_bt(const u16* __restrict__ Ah, const u16* __restrict__ Al,
              const u16* __restrict__ Bh, const u16* __restrict__ Bl,
              int K, int rlim, float* __restrict__ out, int ldo)
{
  __shared__ u16 lAh[128 * 32];
  __shared__ u16 lAl[128 * 32];
  __shared__ u16 lBh[64 * 32];
  __shared__ u16 lBl[64 * 32];
  const int bm = blockIdx.x, bn = blockIdx.y;
  const int tid = threadIdx.x;
  const int wid = tid >> 6, lane = tid & 63;
  const int lcol = lane & 15, khalf = lane >> 4;
  const int kb = khalf * 8;

  f32x4 acc[2][4] = {};

  const u16* Abh = Ah + (size_t)bm * 128 * K;
  const u16* Abl = Al + (size_t)bm * 128 * K;
  const u16* Bbh = Bh + (size_t)bn * 64 * K;
  const u16* Bbl = Bl + (size_t)bn * 64 * K;
  const int arow = wid * 32 + lcol;

  for (int kt = 0; kt < K; kt += 32) {
#pragma unroll
    for (int i = 0; i < 2; ++i) {
      int idx = tid + i * 256;
      int r = idx >> 2, ko = (idx & 3) << 3;
      gload16(Abh + (size_t)r * K + kt + ko, &lAh[idx * 8]);
      gload16(Abl + (size_t)r * K + kt + ko, &lAl[idx * 8]);
    }
    {
      int r = tid >> 2, ko = (tid & 3) << 3;
      gload16(Bbh + (size_t)r * K + kt + ko, &lBh[tid * 8]);
      gload16(Bbl + (size_t)r * K + kt + ko, &lBl[tid * 8]);
    }
    __syncthreads();
    bf16x8 ah[2], al[2], bh[4], bl[4];
#pragma unroll
    for (int f = 0; f < 2; ++f) {
      ah[f] = *(const bf16x8*)&lAh[(arow + f * 16) * 32 + kb];
      al[f] = *(const bf16x8*)&lAl[(arow + f * 16) * 32 + kb];
    }
#pragma unroll
    for (int f = 0; f < 4; ++f) {
      bh[f] = *(const bf16x8*)&lBh[(f * 16 + lcol) * 32 + kb];
      bl[f] = *(const bf16x8*)&lBl[(f * 16 + lcol) * 32 + kb];
    }
#pragma unroll
    for (int m = 0; m < 2; ++m)
#pragma unroll
      for (int n = 0; n < 4; ++n) {
        acc[m][n] = __builtin_amdgcn_mfma_f32_16x16x32_bf16(ah[m], bh[n], acc[m][n], 0, 0, 0);
        acc[m][n] = __builtin_amdgcn_mfma_f32_16x16x32_bf16(ah[m], bl[n], acc[m][n], 0, 0, 0);
        acc[m][n] = __builtin_amdgcn_mfma_f32_16x16x32_bf16(al[m], bh[n], acc[m][n], 0, 0, 0);
        acc[m][n] = __builtin_amdgcn_mfma_f32_16x16x32_bf16(al[m], bl[n], acc[m][n], 0, 0, 0);
      }
    __syncthreads();
  }

  const int r0 = bm * 128 + wid * 32;
#pragma unroll
  for (int fm = 0; fm < 2; ++fm)
#pragma unroll
    for (int i = 0; i < 4; ++i) {
      int row = r0 + fm * 16 + khalf * 4 + i;
      if (row < rlim) {
#pragma unroll
        for (int fn = 0; fn < 4; ++fn) {
          int col = bn * 64 + fn * 16 + lcol;
          out[(size_t)row * ldo + col] = acc[fm][fn][i];
        }
      }
    }
}

// ---------------- LayerNorm (fp32 in -> split bf16 hi/lo out) ----------------
__global__ __launch_bounds__(256)
void ln_kernel(const float* __restrict__ x, const float* __restrict__ g,
               const float* __restrict__ be, u16* __restrict__ h, u16* __restrict__ hl)
{
  const int row = blockIdx.x, tid = threadIdx.x;
  const int wid = tid >> 6, lane = tid & 63;
  const float* xr = x + (size_t)row * D_;
  float4 a = *(const float4*)(xr + tid * 4);
  float4 b = *(const float4*)(xr + 1024 + tid * 4);
  float s = a.x + a.y + a.z + a.w + b.x + b.y + b.z + b.w;
  float q = a.x * a.x + a.y * a.y + a.z * a.z + a.w * a.w +
            b.x * b.x + b.y * b.y + b.z * b.z + b.w * b.w;
#pragma unroll
  for (int d = 1; d < 64; d <<= 1) { s += __shfl_xor(s, d); q += __shfl_xor(q, d); }
  __shared__ float ls[4], lq[4];
  if (lane == 0) { ls[wid] = s; lq[wid] = q; }
  __syncthreads();
  s = ls[0] + ls[1] + ls[2] + ls[3];
  q = lq[0] + lq[1] + lq[2] + lq[3];
  const float mean = s * (1.0f / D_);
  const float var = q * (1.0f / D_) - mean * mean;
  const float rstd = rsqrtf(var + 1e-5f);

#pragma unroll
  for (int half = 0; half < 2; ++half) {
    int base = half * 1024 + tid * 4;
    float4 xv = half ? b : a;
    float4 gv = *(const float4*)(g + base);
    float4 bv = *(const float4*)(be + base);
    float v0 = (xv.x - mean) * rstd * gv.x + bv.x;
    float v1 = (xv.y - mean) * rstd * gv.y + bv.y;
    float v2 = (xv.z - mean) * rstd * gv.z + bv.z;
    float v3 = (xv.w - mean) * rstd * gv.w + bv.w;
    ushort4 oh, ol;
    oh.x = f2bf(v0); ol.x = f2bf(v0 - bf2f(oh.x));
    oh.y = f2bf(v1); ol.y = f2bf(v1 - bf2f(oh.y));
    oh.z = f2bf(v2); ol.z = f2bf(v2 - bf2f(oh.z));
    oh.w = f2bf(v3); ol.w = f2bf(v3 - bf2f(oh.w));
    *(ushort4*)(h  + (size_t)row * D_ + base) = oh;
    *(ushort4*)(hl + (size_t)row * D_ + base) = ol;
  }
}

// ---------------- fp32 -> bf16 cast ----------------
__global__ __launch_bounds__(256)
void castf2b(const float* __restrict__ in, u16* __restrict__ out, int n)
{
  int i = (blockIdx.x * 256 + threadIdx.x) * 4;
  if (i >= n) return;
  float4 v = *(const float4*)(in + i);
  ushort4 o; o.x = f2bf(v.x); o.y = f2bf(v.y); o.z = f2bf(v.z); o.w = f2bf(v.w);
  *(ushort4*)(out + i) = o;
}

// ---------------- fp32 -> bf16 hi/lo split ----------------
__global__ __launch_bounds__(256)
void splitf(const float* __restrict__ in, u16* __restrict__ hi, u16* __restrict__ lo, int n)
{
  int i = (blockIdx.x * 256 + threadIdx.x) * 4;
  if (i >= n) return;
  float4 v = *(const float4*)(in + i);
  ushort4 h, l;
  h.x = f2bf(v.x); l.x = f2bf(v.x - bf2f(h.x));
  h.y = f2bf(v.y); l.y = f2bf(v.y - bf2f(h.y));
  h.z = f2bf(v.z); l.z = f2bf(v.z - bf2f(h.z));
  h.w = f2bf(v.w); l.w = f2bf(v.w - bf2f(h.w));
  *(ushort4*)(hi + i) = h;
  *(ushort4*)(lo + i) = l;
}

// ---------------- WqkT[e][a] = Wq[a][e] + 0.1*Wk[a][e] (split bf16 hi/lo) ----------------
__global__ __launch_bounds__(256)
void wqk_t(const float* __restrict__ Wq, const float* __restrict__ Wk,
           u16* __restrict__ Th, u16* __restrict__ Tl)
{
  __shared__ float t[32][33];
  const int bx = blockIdx.x * 32, by = blockIdx.y * 32;
  const int tx = threadIdx.x & 31, ty = threadIdx.x >> 5;
#pragma unroll
  for (int j = 0; j < 32; j += 8) {
    int aa = by + ty + j, ee = bx + tx;
    t[ty + j][tx] = Wq[(size_t)aa * D_ + ee] + 0.1f * Wk[(size_t)aa * D_ + ee];
  }
  __syncthreads();
#pragma unroll
  for (int j = 0; j < 32; j += 8) {
    int ee = bx + ty + j, aa = by + tx;
    float v = t[tx][ty + j];
    u16 h = f2bf(v);
    Th[(size_t)ee * D_ + aa] = h;
    Tl[(size_t)ee * D_ + aa] = f2bf(v - bf2f(h));
  }
}

// ---------------- reg = sum over tokens of ||q*m|| + ||k*m|| ----------------
__global__ __launch_bounds__(256)
void reg_reduce(const float* __restrict__ qn2, const float* __restrict__ kn2,
                float* __restrict__ racc)
{
  int i = blockIdx.x * 256 + threadIdx.x;
  int lane = threadIdx.x & 63, wid = threadIdx.x >> 6;
  float v = sqrtf(qn2[i]) + sqrtf(kn2[i]);
#pragma unroll
  for (int d = 1; d < 64; d <<= 1) v += __shfl_xor(v, d);
  __shared__ float lsum[4];
  if (lane == 0) lsum[wid] = v;
  __syncthreads();
  if (threadIdx.x == 0) atomicAdd(racc, lsum[0] + lsum[1] + lsum[2] + lsum[3]);
}

// ---------------- softmax/argmax router (lane == channel) ----------------
__global__ __launch_bounds__(256)
void router_kernel(const float* __restrict__ logits, const float* __restrict__ br,
                   int* __restrict__ cid, float* __restrict__ wt, float* __restrict__ chden)
{
  const int tid = threadIdx.x, wid = tid >> 6, lane = tid & 63;
  const int t = blockIdx.x * 4 + wid;
  float l = logits[(size_t)t * C_ + lane] + br[lane];
  float mx = l;
#pragma unroll
  for (int d = 1; d < 64; d <<= 1) mx = fmaxf(mx, __shfl_xor(mx, d));
  float e = __expf(l - mx);
  float s = e;
#pragma unroll
  for (int d = 1; d < 64; d <<= 1) s += __shfl_xor(s, d);
  unsigned long long ball = __ballot(l == mx);
  if (lane == 0) {
    int cstar = __ffsll(ball) - 1;         // first (lowest) index on ties, like argmax
    float ww = 1.0f / s;                   // exp(mx-mx)/s
    cid[t] = cstar;
    wt[t] = ww;
    atomicAdd(&chden[(t >> 12) * C_ + cstar], ww);
  }
}

// ---------------- scatter: partial[b][st][c][dslice] += w * v ----------------
__global__ __launch_bounds__(256)
void scatter_kernel(const u16* __restrict__ v, const int* __restrict__ cid,
                    const float* __restrict__ w, float* __restrict__ partial)
{
  __shared__ float acc[C_ * 256];
  const int b = blockIdx.x, dt = blockIdx.y, st = blockIdx.z;
  const int tid = threadIdx.x;
  for (int i = tid; i < C_ * 256; i += 256) acc[i] = 0.f;
  __syncthreads();
  const int d = dt * 256 + tid;
  const int tbase = b * S_ + st * (S_ / NCH);
  for (int s = 0; s < S_ / NCH; ++s) {
    int t = tbase + s;
    int c = cid[t];
    float ww = w[t];
    acc[c * 256 + tid] += ww * bf2f(v[(size_t)t * D_ + d]);
  }
  __syncthreads();
  float* pb = partial + ((size_t)(b * NCH + st) * C_) * D_ + dt * 256;
  for (int i = tid; i < C_ * 256; i += 256) {
    int c = i >> 8, dd = i & 255;
    pb[(size_t)c * D_ + dd] = acc[i];
  }
}

// ---------------- ch_mean = (sum partials) / (den + eps), bf16 ----------------
__global__ __launch_bounds__(256)
void chmean_kernel(const float* __restrict__ partial, const float* __restrict__ chden,
                   u16* __restrict__ chmean)
{
  int idx = blockIdx.x * 256 + threadIdx.x;       // (b*64+c)*2048+d
  int d = idx & 2047, c = (idx >> 11) & 63, b = idx >> 17;
  float ssum = 0.f;
#pragma unroll
  for (int st = 0; st < NCH; ++st)
    ssum += partial[((size_t)(b * NCH + st) * C_ + c) * D_ + d];
  float den = chden[b * C_ + c];
  chmean[idx] = f2bf(ssum / (den + 1e-8f));
}

// ---------------- out = w*chproj[cid] + bout + reg + x ----------------
__global__ __launch_bounds__(256)
void finalize_kernel(const float* __restrict__ x, const float* __restrict__ bout,
                     const float* __restrict__ chproj, const int* __restrict__ cid,
                     const float* __restrict__ wt, const float* __restrict__ racc,
                     float* __restrict__ out)
{
  const int row = blockIdx.x, tid = threadIdx.x;
  const int b = row >> 12;
  const int c = cid[row];
  const float ww = wt[row];
  const float reg = racc[0] * (0.001f / (float)T_);
  const float* cp = chproj + (size_t)(b * C_ + c) * D_;
  const float* xr = x + (size_t)row * D_;
  float* orow = out + (size_t)row * D_;
#pragma unroll
  for (int base = 0; base < D_; base += 1024) {
    int d = base + tid * 4;
    float4 xv = *(const float4*)(xr + d);
    float4 cv = *(const float4*)(cp + d);
    float4 bv = *(const float4*)(bout + d);
    float4 o;
    o.x = ww * cv.x + bv.x + reg + xv.x;
    o.y = ww * cv.y + bv.y + reg + xv.y;
    o.z = ww * cv.z + bv.z + reg + xv.z;
    o.w = ww * cv.w + bv.w + reg + xv.w;
    *(float4*)(orow + d) = o;
  }
}

extern "C" void kernel_launch(void* const* d_in, const int* in_sizes, int n_in,
                              void* d_out, int out_size, void* d_ws, size_t ws_size,
                              hipStream_t stream)
{
  const float* x     = (const float*)d_in[0];
  const float* mask  = (const float*)d_in[1];
  const float* gamma = (const float*)d_in[2];
  const float* beta  = (const float*)d_in[3];
  const float* Wq    = (const float*)d_in[4];
  const float* Wk    = (const float*)d_in[5];
  const float* Wv    = (const float*)d_in[6];
  const float* Wr    = (const float*)d_in[7];
  const float* br    = (const float*)d_in[8];
  const float* Wa    = (const float*)d_in[9];
  const float* ba    = (const float*)d_in[10];
  const float* Wout  = (const float*)d_in[11];
  const float* bout  = (const float*)d_in[12];
  float* out = (float*)d_out;

  char* p = (char*)d_ws;
  size_t off = 0;
  auto take = [&](size_t bytes) -> void* {
    void* r = p + off;
    off = (off + bytes + 255) & ~(size_t)255;
    return r;
  };

  u16*   Wall   = (u16*)take((size_t)NALL * D_ * 2);
  u16*   WrPh   = (u16*)take((size_t)128 * D_ * 2);
  u16*   WrPl   = (u16*)take((size_t)128 * D_ * 2);
  u16*   Wqkh   = (u16*)take((size_t)D_ * D_ * 2);
  u16*   Wqkl   = (u16*)take((size_t)D_ * D_ * 2);
  u16*   WaB    = (u16*)take((size_t)D_ * D_ * 2);
  u16*   WoutB  = (u16*)take((size_t)D_ * D_ * 2);
  u16*   hbuf   = (u16*)take((size_t)T_ * D_ * 2);
  u16*   hlbuf  = (u16*)take((size_t)T_ * D_ * 2);
  u16*   vbuf   = (u16*)take((size_t)T_ * D_ * 2);
  float* Mf     = (float*)take((size_t)C_ * D_ * 4);
  u16*   Mh     = (u16*)take((size_t)C_ * D_ * 2);
  u16*   Ml     = (u16*)take((size_t)C_ * D_ * 2);
  float* logits = (float*)take((size_t)T_ * C_ * 4);
  float* partial= (float*)take((size_t)B_ * NCH * C_ * D_ * 4);
  float* chproj = (float*)take((size_t)B_ * C_ * D_ * 4);
  u16*   chmean = (u16*)take((size_t)B_ * C_ * D_ * 2);
  u16*   choutb = (u16*)take((size_t)B_ * C_ * D_ * 2);
  int*   cid    = (int*)take((size_t)T_ * 4);
  float* wt     = (float*)take((size_t)T_ * 4);
  char*  zbeg   = p + off;                       // ---- zeroed-every-call region ----
  float* qn2    = (float*)take((size_t)T_ * 4);
  float* kn2    = (float*)take((size_t)T_ * 4);
  float* chden  = (float*)take((size_t)B_ * C_ * 4);
  float* racc   = (float*)take(256);
  size_t zlen   = (size_t)((p + off) - zbeg);

  hipMemsetAsync(zbeg, 0, zlen, stream);
  hipMemsetAsync(WrPh + (size_t)C_ * D_, 0, (size_t)C_ * D_ * 2, stream);  // pad rows 64..127
  hipMemsetAsync(WrPl + (size_t)C_ * D_, 0, (size_t)C_ * D_ * 2, stream);

  const int cb = 256;
  castf2b<<<dim3((D_ * D_) / 1024), cb, 0, stream>>>(Wq, Wall, D_ * D_);
  castf2b<<<dim3((D_ * D_) / 1024), cb, 0, stream>>>(Wk, Wall + (size_t)D_ * D_, D_ * D_);
  castf2b<<<dim3((D_ * D_) / 1024), cb, 0, stream>>>(Wv, Wall + (size_t)2 * D_ * D_, D_ * D_);
  castf2b<<<dim3((D_ * D_) / 1024), cb, 0, stream>>>(Wa, WaB, D_ * D_);
  castf2b<<<dim3((D_ * D_) / 1024), cb, 0, stream>>>(Wout, WoutB, D_ * D_);
  splitf<<<dim3((C_ * D_) / 1024), cb, 0, stream>>>(Wr, WrPh, WrPl, C_ * D_);
  wqk_t<<<dim3(64, 64), cb, 0, stream>>>(Wq, Wk, Wqkh, Wqkl);
  ln_kernel<<<dim3(T_), cb, 0, stream>>>(x, gamma, beta, hbuf, hlbuf);

  // M = Wr @ (Wq + 0.1 Wk)  -- split-precision exact, fp32 out [64][2048]
  gemm4_bt<<<dim3(1, D_ / 64), cb, 0, stream>>>(WrPh, WrPl, Wqkh, Wqkl, D_, C_, Mf, D_);
  splitf<<<dim3((C_ * D_) / 1024), cb, 0, stream>>>(Mf, Mh, Ml, C_ * D_);
  // logits = h @ M^T  -- split-precision exact, fp32 out [T][64]
  gemm4_bt<<<dim3(T_ / 128, 1), cb, 0, stream>>>(hbuf, hlbuf, Mh, Ml, D_, T_, logits, C_);

  // fused q/k norms + v
  gemm_bt<0><<<dim3(T_ / 128, NALL / 128), cb, 0, stream>>>(hbuf, Wall, D_, mask, qn2, kn2,
                                                            vbuf, nullptr, nullptr);
  reg_reduce<<<dim3(T_ / 256), cb, 0, stream>>>(qn2, kn2, racc);
  router_kernel<<<dim3(T_ / 4), cb, 0, stream>>>(logits, br, cid, wt, chden);
  scatter_kernel<<<dim3(B_, D_ / 256, NCH), cb, 0, stream>>>(vbuf, cid, wt, partial);
  chmean_kernel<<<dim3((B_ * C_ * D_) / 256), cb, 0, stream>>>(partial, chden, chmean);
  // ch_out = ch_mean @ Wa^T + ba (bf16)
  gemm_bt<2><<<dim3(2, 16), cb, 0, stream>>>(chmean, WaB, D_, nullptr, nullptr, nullptr,
                                             choutb, nullptr, ba);
  // chproj = ch_out @ Wout^T (fp32)
  gemm_bt<3><<<dim3(2, 16), cb, 0, stream>>>(choutb, WoutB, D_, nullptr, nullptr, nullptr,
                                             nullptr, chproj, nullptr);
  finalize_kernel<<<dim3(T_), cb, 0, stream>>>(x, bout, chproj, cid, wt, racc, out);
}

// Round 4
// 1078.030 us; speedup vs baseline: 1.1912x; 1.1912x over previous
//
#include <hip/hip_runtime.h>
#include <hip/hip_bf16.h>

typedef unsigned short u16;
typedef __bf16 bf16x8 __attribute__((ext_vector_type(8)));
typedef float  f32x4  __attribute__((ext_vector_type(4)));

#define B_   4
#define S_   4096
#define D_   2048
#define C_   64
#define T_   (B_*S_)      // 16384 tokens
#define NALL 6144         // 3*D (q,k,v)
#define NCH  16           // token chunks per batch for scatter

__device__ __forceinline__ u16 f2bf(float f) {
  union { float f; unsigned u; } c; c.f = f;
  unsigned r = c.u + 0x7FFFu + ((c.u >> 16) & 1u);
  return (u16)(r >> 16);
}
__device__ __forceinline__ float bf2f(u16 u) {
  union { float f; unsigned u; } c; c.u = ((unsigned)u) << 16;
  return c.f;
}

__device__ __forceinline__ void gload16(const u16* g, u16* l) {
  __builtin_amdgcn_global_load_lds(
      (__attribute__((address_space(1))) void*)(void*)g,
      (__attribute__((address_space(3))) void*)l, 16, 0, 0);
}

#define BAR()  { __builtin_amdgcn_s_barrier(); __builtin_amdgcn_sched_barrier(0); }
#define VMW(N) { asm volatile("s_waitcnt vmcnt(" #N ")" ::: "memory"); __builtin_amdgcn_sched_barrier(0); }

// ================= 256x256 8-phase fused QKV GEMM =================
// C[16384, 6144] = A[16384,2048] @ B[6144,2048]^T, A=h bf16, B=Wall bf16.
// 512 thr = 8 waves (2M x 4N), per-wave C 128x64 (acc[8][4]).
// LDS 128KB: 2 bufs x (A 256x64 + B 256x64) bf16. XOR swizzle: 16B-chunk cc
// stores k-chunk kc = cc ^ (row&7)  -> conflict-free ds_read_b128 (2 lanes/quad).
// Half-tile stage units (16KB, 2 gload_lds/wave):
//   B0=B rows 0-127, B1=128-255, Aa=A rows 0-63&128-191, Ab=64-127&192-255.
// Per K-tile group (4 phases), staging tile kt+1 into buf^1:
//   p1: dsB(8)+dsA m0-3(8); stage B0; bar; mfma m0-3 x n0-1; bar;
//   p2: stage B1; bar; mfma m0-3 x n2-3; VM(4); bar;   (certifies Ab(kt))
//   p3: dsA m4-7(8); stage Aa; bar; mfma m4-7 x n0-1; bar;
//   p4: stage Ab; bar; mfma m4-7 x n2-3; VM(2); bar;   (certifies B0,B1,Aa(kt+1))
// Ledger: every region staged is >=4 phases past its last read; reads are
// vmcnt+barrier-certified. Last iteration's prefetch wraps to k=0 (in-bounds,
// result never read).
template<int REGB, int TYPE>
__device__ __forceinline__ void stage_ht(const u16* __restrict__ Mat, char* lds,
                                         int bufbyte, int kelem, int wid, int lane)
{
#pragma unroll
  for (int j = 0; j < 2; ++j) {
    int sr;
    if (TYPE == 0)      sr = (j ?  64 :   0) + wid * 8;   // B0
    else if (TYPE == 1) sr = (j ? 192 : 128) + wid * 8;   // B1
    else if (TYPE == 2) sr = (j ? 128 :   0) + wid * 8;   // Aa
    else                sr = (j ? 192 :  64) + wid * 8;   // Ab
    int r  = sr + (lane >> 3);
    int kc = (lane & 7) ^ (lane >> 3);
    const u16* src = Mat + (size_t)r * 2048 + kelem + kc * 8;
    u16* dst = (u16*)(lds + bufbyte + REGB * 32768 + sr * 128 + lane * 16);
    gload16(src, dst);
  }
}

__global__ __launch_bounds__(512, 2)
void qkv8(const u16* __restrict__ A, const u16* __restrict__ BT,
          const float* __restrict__ mask,
          float* __restrict__ qn2, float* __restrict__ kn2,
          u16* __restrict__ vout)
{
  extern __shared__ char lds[];
  const int tid = threadIdx.x;
  const int wid = tid >> 6, lane = tid & 63;
  const int wm = wid >> 2, wn = wid & 3;
  const int lcol = lane & 15, lhi = lane >> 4, lc7 = lane & 7;
  const int bm = blockIdx.x, bn = blockIdx.y;

  const u16* Ab_ = A  + (size_t)bm * 256 * 2048;
  const u16* Bb_ = BT + (size_t)bn * 256 * 2048;

  f32x4 acc[8][4] = {};
  bf16x8 afr[4][2], bfr[4][2];

#define LDA_(f_, s_) (*(const bf16x8*)(lds + cbyte + ((wm*128 + (f_)*16 + lcol) * 128) + (((lhi + (s_)*4) ^ lc7) << 4)))
#define LDB_(g_, s_) (*(const bf16x8*)(lds + cbyte + 32768 + ((wn*64 + (g_)*16 + lcol) * 128) + (((lhi + (s_)*4) ^ lc7) << 4)))

  // ---- prologue: stage tile 0 into buf0 ----
  stage_ht<1, 0>(Bb_, lds, 0, 0, wid, lane);
  stage_ht<1, 1>(Bb_, lds, 0, 0, wid, lane);
  stage_ht<0, 2>(Ab_, lds, 0, 0, wid, lane);
  stage_ht<0, 3>(Ab_, lds, 0, 0, wid, lane);
  VMW(2); BAR();

#pragma unroll 2
  for (int kt = 0; kt < 32; ++kt) {
    const int cbyte = (kt & 1) * 65536;
    const int nbyte = cbyte ^ 65536;
    const int kel = ((kt + 1) & 31) * 64;   // wraps on last iter (dead prefetch, in-bounds)

    // ---- phase 1 ----
#pragma unroll
    for (int g = 0; g < 4; ++g)
#pragma unroll
      for (int s = 0; s < 2; ++s) bfr[g][s] = LDB_(g, s);
#pragma unroll
    for (int f = 0; f < 4; ++f)
#pragma unroll
      for (int s = 0; s < 2; ++s) afr[f][s] = LDA_(f, s);
    stage_ht<1, 0>(Bb_, lds, nbyte, kel, wid, lane);
    BAR();
    __builtin_amdgcn_s_setprio(1);
#pragma unroll
    for (int f = 0; f < 4; ++f)
#pragma unroll
      for (int g = 0; g < 2; ++g)
#pragma unroll
        for (int s = 0; s < 2; ++s)
          acc[f][g] = __builtin_amdgcn_mfma_f32_16x16x32_bf16(afr[f][s], bfr[g][s], acc[f][g], 0, 0, 0);
    __builtin_amdgcn_s_setprio(0);
    BAR();

    // ---- phase 2 ----
    stage_ht<1, 1>(Bb_, lds, nbyte, kel, wid, lane);
    BAR();
    __builtin_amdgcn_s_setprio(1);
#pragma unroll
    for (int f = 0; f < 4; ++f)
#pragma unroll
      for (int g = 2; g < 4; ++g)
#pragma unroll
        for (int s = 0; s < 2; ++s)
          acc[f][g] = __builtin_amdgcn_mfma_f32_16x16x32_bf16(afr[f][s], bfr[g][s], acc[f][g], 0, 0, 0);
    __builtin_amdgcn_s_setprio(0);
    VMW(4); BAR();

    // ---- phase 3 ----
#pragma unroll
    for (int f = 0; f < 4; ++f)
#pragma unroll
      for (int s = 0; s < 2; ++s) afr[f][s] = LDA_(f + 4, s);
    stage_ht<0, 2>(Ab_, lds, nbyte, kel, wid, lane);
    BAR();
    __builtin_amdgcn_s_setprio(1);
#pragma unroll
    for (int f = 0; f < 4; ++f)
#pragma unroll
      for (int g = 0; g < 2; ++g)
#pragma unroll
        for (int s = 0; s < 2; ++s)
          acc[f + 4][g] = __builtin_amdgcn_mfma_f32_16x16x32_bf16(afr[f][s], bfr[g][s], acc[f + 4][g], 0, 0, 0);
    __builtin_amdgcn_s_setprio(0);
    BAR();

    // ---- phase 4 ----
    stage_ht<0, 3>(Ab_, lds, nbyte, kel, wid, lane);
    BAR();
    __builtin_amdgcn_s_setprio(1);
#pragma unroll
    for (int f = 0; f < 4; ++f)
#pragma unroll
      for (int g = 2; g < 4; ++g)
#pragma unroll
        for (int s = 0; s < 2; ++s)
          acc[f + 4][g] = __builtin_amdgcn_mfma_f32_16x16x32_bf16(afr[f][s], bfr[g][s], acc[f + 4][g], 0, 0, 0);
    __builtin_amdgcn_s_setprio(0);
    VMW(2); BAR();
  }
#undef LDA_
#undef LDB_

  // ---- epilogue ----
  const int region = bn >> 3;          // 0:q 1:k 2:v
  const int grow0 = bm * 256 + wm * 128;
  if (region < 2) {
    float* dst = region ? kn2 : qn2;
#pragma unroll
    for (int f = 0; f < 8; ++f)
#pragma unroll
      for (int i = 0; i < 4; ++i) {
        int row = grow0 + f * 16 + lhi * 4 + i;
        float mv = mask[row];
        float ss = 0.f;
#pragma unroll
        for (int g = 0; g < 4; ++g) { float v = acc[f][g][i] * mv; ss += v * v; }
#pragma unroll
        for (int d = 1; d < 16; d <<= 1) ss += __shfl_xor(ss, d);
        if (lcol == 0) atomicAdd(dst + row, ss);
      }
  } else {
    const int gcol0 = (bn - 16) * 256 + wn * 64 + lcol;
#pragma unroll
    for (int f = 0; f < 8; ++f)
#pragma unroll
      for (int i = 0; i < 4; ++i) {
        int row = grow0 + f * 16 + lhi * 4 + i;
        float mv = mask[row];
#pragma unroll
        for (int g = 0; g < 4; ++g)
          vout[(size_t)row * D_ + gcol0 + g * 16] = f2bf(acc[f][g][i] * mv);
      }
  }
}

// ---------------- generic 128x128 bt-GEMM (A [M,K] bf16, BT [N,K] bf16) ----------------
// LDS [r][32] with 2-way XOR swizzle: k-chunk kc stored at chunk kc^((r>>1)&3).
// EPI 2: +bias, write bf16 (ch_out) | EPI 3: write fp32 (chproj)
template<int EPI>
__global__ __launch_bounds__(256)
void gemm_bt(const u16* __restrict__ A, const u16* __restrict__ BT, int K,
             u16* __restrict__ uout, float* __restrict__ fout,
             const float* __restrict__ bias)
{
  __shared__ u16 lA[128 * 32];
  __shared__ u16 lB[128 * 32];
  const int bm = blockIdx.x, bn = blockIdx.y;
  const int tid = threadIdx.x;
  const int wid = tid >> 6, lane = tid & 63;
  const int wm = wid >> 1, wn = wid & 1;
  const int lcol = lane & 15, khalf = lane >> 4;
  const int csw = khalf ^ ((lcol >> 1) & 3);   // swizzled chunk for reads
  const int kb = csw * 8;

  f32x4 acc[4][4] = {};

  const u16* Ab = A + (size_t)bm * 128 * K;
  const u16* Bb = BT + (size_t)bn * 128 * K;
  const int arow = wm * 64 + lcol;
  const int brow = wn * 64 + lcol;

  for (int kt = 0; kt < K; kt += 32) {
#pragma unroll
    for (int i = 0; i < 2; ++i) {
      int idx = tid + i * 256;
      int r = idx >> 2;
      int kc = (idx & 3) ^ ((r >> 1) & 3);
      int ko = kc << 3;
      gload16(Ab + (size_t)r * K + kt + ko, &lA[idx * 8]);
      gload16(Bb + (size_t)r * K + kt + ko, &lB[idx * 8]);
    }
    __syncthreads();
    bf16x8 av[4], bv[4];
#pragma unroll
    for (int f = 0; f < 4; ++f) {
      av[f] = *(const bf16x8*)&lA[(arow + f * 16) * 32 + kb];
      bv[f] = *(const bf16x8*)&lB[(brow + f * 16) * 32 + kb];
    }
#pragma unroll
    for (int m = 0; m < 4; ++m)
#pragma unroll
      for (int n = 0; n < 4; ++n)
        acc[m][n] = __builtin_amdgcn_mfma_f32_16x16x32_bf16(av[m], bv[n], acc[m][n], 0, 0, 0);
    __syncthreads();
  }

  const int r0 = bm * 128 + wm * 64;
  const int c0 = bn * 128 + wn * 64;
  const int lrow = khalf * 4;

  if constexpr (EPI == 2) {
#pragma unroll
    for (int fm = 0; fm < 4; ++fm)
#pragma unroll
      for (int i = 0; i < 4; ++i) {
        int row = r0 + fm * 16 + lrow + i;
#pragma unroll
        for (int fn = 0; fn < 4; ++fn) {
          int col = c0 + fn * 16 + lcol;
          uout[(size_t)row * D_ + col] = f2bf(acc[fm][fn][i] + bias[col]);
        }
      }
  } else {
#pragma unroll
    for (int fm = 0; fm < 4; ++fm)
#pragma unroll
      for (int i = 0; i < 4; ++i) {
        int row = r0 + fm * 16 + lrow + i;
#pragma unroll
        for (int fn = 0; fn < 4; ++fn) {
          int col = c0 + fn * 16 + lcol;
          fout[(size_t)row * D_ + col] = acc[fm][fn][i];
        }
      }
  }
}

// ---------------- split-precision GEMM: out = (Ah+Al) @ (Bh+Bl)^T, fp32 out ----------------
// Same 2-way XOR swizzle as gemm_bt.
__global__ __launch_bounds__(256)
void gemm4_bt(const u16* __restrict__ Ah, const u16* __restrict__ Al,
              const u16* __restrict__ Bh, const u16* __restrict__ Bl,
              int K, int rlim, float* __restrict__ out, int ldo)
{
  __shared__ u16 lAh[128 * 32];
  __shared__ u16 lAl[128 * 32];
  __shared__ u16 lBh[64 * 32];
  __shared__ u16 lBl[64 * 32];
  const int bm = blockIdx.x, bn = blockIdx.y;
  const int tid = threadIdx.x;
  const int wid = tid >> 6, lane = tid & 63;
  const int lcol = lane & 15, khalf = lane >> 4;
  const int csw = khalf ^ ((lcol >> 1) & 3);
  const int kb = csw * 8;

  f32x4 acc[2][4] = {};

  const u16* Abh = Ah + (size_t)bm * 128 * K;
  const u16* Abl = Al + (size_t)bm * 128 * K;
  const u16* Bbh = Bh + (size_t)bn * 64 * K;
  const u16* Bbl = Bl + (size_t)bn * 64 * K;
  const int arow = wid * 32 + lcol;

  for (int kt = 0; kt < K; kt += 32) {
#pragma unroll
    for (int i = 0; i < 2; ++i) {
      int idx = tid + i * 256;
      int r = idx >> 2;
      int kc = (idx & 3) ^ ((r >> 1) & 3);
      int ko = kc << 3;
      gload16(Abh + (size_t)r * K + kt + ko, &lAh[idx * 8]);
      gload16(Abl + (size_t)r * K + kt + ko, &lAl[idx * 8]);
    }
    {
      int r = tid >> 2;
      int kc = (tid & 3) ^ ((r >> 1) & 3);
      int ko = kc << 3;
      gload16(Bbh + (size_t)r * K + kt + ko, &lBh[tid * 8]);
      gload16(Bbl + (size_t)r * K + kt + ko, &lBl[tid * 8]);
    }
    __syncthreads();
    bf16x8 ah[2], al[2], bh[4], bl[4];
#pragma unroll
    for (int f = 0; f < 2; ++f) {
      ah[f] = *(const bf16x8*)&lAh[(arow + f * 16) * 32 + kb];
      al[f] = *(const bf16x8*)&lAl[(arow + f * 16) * 32 + kb];
    }
#pragma unroll
    for (int f = 0; f < 4; ++f) {
      bh[f] = *(const bf16x8*)&lBh[(f * 16 + lcol) * 32 + kb];
      bl[f] = *(const bf16x8*)&lBl[(f * 16 + lcol) * 32 + kb];
    }
#pragma unroll
    for (int m = 0; m < 2; ++m)
#pragma unroll
      for (int n = 0; n < 4; ++n) {
        acc[m][n] = __builtin_amdgcn_mfma_f32_16x16x32_bf16(ah[m], bh[n], acc[m][n], 0, 0, 0);
        acc[m][n] = __builtin_amdgcn_mfma_f32_16x16x32_bf16(ah[m], bl[n], acc[m][n], 0, 0, 0);
        acc[m][n] = __builtin_amdgcn_mfma_f32_16x16x32_bf16(al[m], bh[n], acc[m][n], 0, 0, 0);
        acc[m][n] = __builtin_amdgcn_mfma_f32_16x16x32_bf16(al[m], bl[n], acc[m][n], 0, 0, 0);
      }
    __syncthreads();
  }

  const int r0 = bm * 128 + wid * 32;
#pragma unroll
  for (int fm = 0; fm < 2; ++fm)
#pragma unroll
    for (int i = 0; i < 4; ++i) {
      int row = r0 + fm * 16 + khalf * 4 + i;
      if (row < rlim) {
#pragma unroll
        for (int fn = 0; fn < 4; ++fn) {
          int col = bn * 64 + fn * 16 + lcol;
          out[(size_t)row * ldo + col] = acc[fm][fn][i];
        }
      }
    }
}

// ---------------- LayerNorm (fp32 in -> split bf16 hi/lo out) ----------------
__global__ __launch_bounds__(256)
void ln_kernel(const float* __restrict__ x, const float* __restrict__ g,
               const float* __restrict__ be, u16* __restrict__ h, u16* __restrict__ hl)
{
  const int row = blockIdx.x, tid = threadIdx.x;
  const int wid = tid >> 6, lane = tid & 63;
  const float* xr = x + (size_t)row * D_;
  float4 a = *(const float4*)(xr + tid * 4);
  float4 b = *(const float4*)(xr + 1024 + tid * 4);
  float s = a.x + a.y + a.z + a.w + b.x + b.y + b.z + b.w;
  float q = a.x * a.x + a.y * a.y + a.z * a.z + a.w * a.w +
            b.x * b.x + b.y * b.y + b.z * b.z + b.w * b.w;
#pragma unroll
  for (int d = 1; d < 64; d <<= 1) { s += __shfl_xor(s, d); q += __shfl_xor(q, d); }
  __shared__ float ls[4], lq[4];
  if (lane == 0) { ls[wid] = s; lq[wid] = q; }
  __syncthreads();
  s = ls[0] + ls[1] + ls[2] + ls[3];
  q = lq[0] + lq[1] + lq[2] + lq[3];
  const float mean = s * (1.0f / D_);
  const float var = q * (1.0f / D_) - mean * mean;
  const float rstd = rsqrtf(var + 1e-5f);

#pragma unroll
  for (int half = 0; half < 2; ++half) {
    int base = half * 1024 + tid * 4;
    float4 xv = half ? b : a;
    float4 gv = *(const float4*)(g + base);
    float4 bv = *(const float4*)(be + base);
    float v0 = (xv.x - mean) * rstd * gv.x + bv.x;
    float v1 = (xv.y - mean) * rstd * gv.y + bv.y;
    float v2 = (xv.z - mean) * rstd * gv.z + bv.z;
    float v3 = (xv.w - mean) * rstd * gv.w + bv.w;
    ushort4 oh, ol;
    oh.x = f2bf(v0); ol.x = f2bf(v0 - bf2f(oh.x));
    oh.y = f2bf(v1); ol.y = f2bf(v1 - bf2f(oh.y));
    oh.z = f2bf(v2); ol.z = f2bf(v2 - bf2f(oh.z));
    oh.w = f2bf(v3); ol.w = f2bf(v3 - bf2f(oh.w));
    *(ushort4*)(h  + (size_t)row * D_ + base) = oh;
    *(ushort4*)(hl + (size_t)row * D_ + base) = ol;
  }
}

// ---------------- fp32 -> bf16 cast ----------------
__global__ __launch_bounds__(256)
void castf2b(const float* __restrict__ in, u16* __restrict__ out, int n)
{
  int i = (blockIdx.x * 256 + threadIdx.x) * 4;
  if (i >= n) return;
  float4 v = *(const float4*)(in + i);
  ushort4 o; o.x = f2bf(v.x); o.y = f2bf(v.y); o.z = f2bf(v.z); o.w = f2bf(v.w);
  *(ushort4*)(out + i) = o;
}

// ---------------- fp32 -> bf16 hi/lo split ----------------
__global__ __launch_bounds__(256)
void splitf(const float* __restrict__ in, u16* __restrict__ hi, u16* __restrict__ lo, int n)
{
  int i = (blockIdx.x * 256 + threadIdx.x) * 4;
  if (i >= n) return;
  float4 v = *(const float4*)(in + i);
  ushort4 h, l;
  h.x = f2bf(v.x); l.x = f2bf(v.x - bf2f(h.x));
  h.y = f2bf(v.y); l.y = f2bf(v.y - bf2f(h.y));
  h.z = f2bf(v.z); l.z = f2bf(v.z - bf2f(h.z));
  h.w = f2bf(v.w); l.w = f2bf(v.w - bf2f(h.w));
  *(ushort4*)(hi + i) = h;
  *(ushort4*)(lo + i) = l;
}

// ---------------- WqkT[e][a] = Wq[a][e] + 0.1*Wk[a][e] (split bf16 hi/lo) ----------------
__global__ __launch_bounds__(256)
void wqk_t(const float* __restrict__ Wq, const float* __restrict__ Wk,
           u16* __restrict__ Th, u16* __restrict__ Tl)
{
  __shared__ float t[32][33];
  const int bx = blockIdx.x * 32, by = blockIdx.y * 32;
  const int tx = threadIdx.x & 31, ty = threadIdx.x >> 5;
#pragma unroll
  for (int j = 0; j < 32; j += 8) {
    int aa = by + ty + j, ee = bx + tx;
    t[ty + j][tx] = Wq[(size_t)aa * D_ + ee] + 0.1f * Wk[(size_t)aa * D_ + ee];
  }
  __syncthreads();
#pragma unroll
  for (int j = 0; j < 32; j += 8) {
    int ee = bx + ty + j, aa = by + tx;
    float v = t[tx][ty + j];
    u16 h = f2bf(v);
    Th[(size_t)ee * D_ + aa] = h;
    Tl[(size_t)ee * D_ + aa] = f2bf(v - bf2f(h));
  }
}

// ---------------- reg = sum over tokens of ||q*m|| + ||k*m|| ----------------
__global__ __launch_bounds__(256)
void reg_reduce(const float* __restrict__ qn2, const float* __restrict__ kn2,
                float* __restrict__ racc)
{
  int i = blockIdx.x * 256 + threadIdx.x;
  int lane = threadIdx.x & 63, wid = threadIdx.x >> 6;
  float v = sqrtf(qn2[i]) + sqrtf(kn2[i]);
#pragma unroll
  for (int d = 1; d < 64; d <<= 1) v += __shfl_xor(v, d);
  __shared__ float lsum[4];
  if (lane == 0) lsum[wid] = v;
  __syncthreads();
  if (threadIdx.x == 0) atomicAdd(racc, lsum[0] + lsum[1] + lsum[2] + lsum[3]);
}

// ---------------- softmax/argmax router (lane == channel) ----------------
__global__ __launch_bounds__(256)
void router_kernel(const float* __restrict__ logits, const float* __restrict__ br,
                   int* __restrict__ cid, float* __restrict__ wt, float* __restrict__ chden)
{
  const int tid = threadIdx.x, wid = tid >> 6, lane = tid & 63;
  const int t = blockIdx.x * 4 + wid;
  float l = logits[(size_t)t * C_ + lane] + br[lane];
  float mx = l;
#pragma unroll
  for (int d = 1; d < 64; d <<= 1) mx = fmaxf(mx, __shfl_xor(mx, d));
  float e = __expf(l - mx);
  float s = e;
#pragma unroll
  for (int d = 1; d < 64; d <<= 1) s += __shfl_xor(s, d);
  unsigned long long ball = __ballot(l == mx);
  if (lane == 0) {
    int cstar = __ffsll(ball) - 1;
    float ww = 1.0f / s;
    cid[t] = cstar;
    wt[t] = ww;
    atomicAdd(&chden[(t >> 12) * C_ + cstar], ww);
  }
}

// ---------------- scatter: partial[b][st][c][dslice] += w * v ----------------
__global__ __launch_bounds__(256)
void scatter_kernel(const u16* __restrict__ v, const int* __restrict__ cid,
                    const float* __restrict__ w, float* __restrict__ partial)
{
  __shared__ float acc[C_ * 256];
  const int b = blockIdx.x, dt = blockIdx.y, st = blockIdx.z;
  const int tid = threadIdx.x;
  for (int i = tid; i < C_ * 256; i += 256) acc[i] = 0.f;
  __syncthreads();
  const int d = dt * 256 + tid;
  const int tbase = b * S_ + st * (S_ / NCH);
  for (int s = 0; s < S_ / NCH; ++s) {
    int t = tbase + s;
    int c = cid[t];
    float ww = w[t];
    acc[c * 256 + tid] += ww * bf2f(v[(size_t)t * D_ + d]);
  }
  __syncthreads();
  float* pb = partial + ((size_t)(b * NCH + st) * C_) * D_ + dt * 256;
  for (int i = tid; i < C_ * 256; i += 256) {
    int c = i >> 8, dd = i & 255;
    pb[(size_t)c * D_ + dd] = acc[i];
  }
}

// ---------------- ch_mean = (sum partials) / (den + eps), bf16 ----------------
__global__ __launch_bounds__(256)
void chmean_kernel(const float* __restrict__ partial, const float* __restrict__ chden,
                   u16* __restrict__ chmean)
{
  int idx = blockIdx.x * 256 + threadIdx.x;
  int d = idx & 2047, c = (idx >> 11) & 63, b = idx >> 17;
  float ssum = 0.f;
#pragma unroll
  for (int st = 0; st < NCH; ++st)
    ssum += partial[((size_t)(b * NCH + st) * C_ + c) * D_ + d];
  float den = chden[b * C_ + c];
  chmean[idx] = f2bf(ssum / (den + 1e-8f));
}

// ---------------- out = w*chproj[cid] + bout + reg + x ----------------
__global__ __launch_bounds__(256)
void finalize_kernel(const float* __restrict__ x, const float* __restrict__ bout,
                     const float* __restrict__ chproj, const int* __restrict__ cid,
                     const float* __restrict__ wt, const float* __restrict__ racc,
                     float* __restrict__ out)
{
  const int row = blockIdx.x, tid = threadIdx.x;
  const int b = row >> 12;
  const int c = cid[row];
  const float ww = wt[row];
  const float reg = racc[0] * (0.001f / (float)T_);
  const float* cp = chproj + (size_t)(b * C_ + c) * D_;
  const float* xr = x + (size_t)row * D_;
  float* orow = out + (size_t)row * D_;
#pragma unroll
  for (int base = 0; base < D_; base += 1024) {
    int d = base + tid * 4;
    float4 xv = *(const float4*)(xr + d);
    float4 cv = *(const float4*)(cp + d);
    float4 bv = *(const float4*)(bout + d);
    float4 o;
    o.x = ww * cv.x + bv.x + reg + xv.x;
    o.y = ww * cv.y + bv.y + reg + xv.y;
    o.z = ww * cv.z + bv.z + reg + xv.z;
    o.w = ww * cv.w + bv.w + reg + xv.w;
    *(float4*)(orow + d) = o;
  }
}

extern "C" void kernel_launch(void* const* d_in, const int* in_sizes, int n_in,
                              void* d_out, int out_size, void* d_ws, size_t ws_size,
                              hipStream_t stream)
{
  const float* x     = (const float*)d_in[0];
  const float* mask  = (const float*)d_in[1];
  const float* gamma = (const float*)d_in[2];
  const float* beta  = (const float*)d_in[3];
  const float* Wq    = (const float*)d_in[4];
  const float* Wk    = (const float*)d_in[5];
  const float* Wv    = (const float*)d_in[6];
  const float* Wr    = (const float*)d_in[7];
  const float* br    = (const float*)d_in[8];
  const float* Wa    = (const float*)d_in[9];
  const float* ba    = (const float*)d_in[10];
  const float* Wout  = (const float*)d_in[11];
  const float* bout  = (const float*)d_in[12];
  float* out = (float*)d_out;

  char* p = (char*)d_ws;
  size_t off = 0;
  auto take = [&](size_t bytes) -> void* {
    void* r = p + off;
    off = (off + bytes + 255) & ~(size_t)255;
    return r;
  };

  u16*   Wall   = (u16*)take((size_t)NALL * D_ * 2);
  u16*   WrPh   = (u16*)take((size_t)128 * D_ * 2);
  u16*   WrPl   = (u16*)take((size_t)128 * D_ * 2);
  u16*   Wqkh   = (u16*)take((size_t)D_ * D_ * 2);
  u16*   Wqkl   = (u16*)take((size_t)D_ * D_ * 2);
  u16*   WaB    = (u16*)take((size_t)D_ * D_ * 2);
  u16*   WoutB  = (u16*)take((size_t)D_ * D_ * 2);
  u16*   hbuf   = (u16*)take((size_t)T_ * D_ * 2);
  u16*   hlbuf  = (u16*)take((size_t)T_ * D_ * 2);
  u16*   vbuf   = (u16*)take((size_t)T_ * D_ * 2);
  float* Mf     = (float*)take((size_t)C_ * D_ * 4);
  u16*   Mh     = (u16*)take((size_t)C_ * D_ * 2);
  u16*   Ml     = (u16*)take((size_t)C_ * D_ * 2);
  float* logits = (float*)take((size_t)T_ * C_ * 4);
  float* partial= (float*)take((size_t)B_ * NCH * C_ * D_ * 4);
  float* chproj = (float*)take((size_t)B_ * C_ * D_ * 4);
  u16*   chmean = (u16*)take((size_t)B_ * C_ * D_ * 2);
  u16*   choutb = (u16*)take((size_t)B_ * C_ * D_ * 2);
  int*   cid    = (int*)take((size_t)T_ * 4);
  float* wt     = (float*)take((size_t)T_ * 4);
  char*  zbeg   = p + off;                       // ---- zeroed-every-call region ----
  float* qn2    = (float*)take((size_t)T_ * 4);
  float* kn2    = (float*)take((size_t)T_ * 4);
  float* chden  = (float*)take((size_t)B_ * C_ * 4);
  float* racc   = (float*)take(256);
  size_t zlen   = (size_t)((p + off) - zbeg);

  hipMemsetAsync(zbeg, 0, zlen, stream);
  hipMemsetAsync(WrPh + (size_t)C_ * D_, 0, (size_t)C_ * D_ * 2, stream);
  hipMemsetAsync(WrPl + (size_t)C_ * D_, 0, (size_t)C_ * D_ * 2, stream);

  const int cb = 256;
  castf2b<<<dim3((D_ * D_) / 1024), cb, 0, stream>>>(Wq, Wall, D_ * D_);
  castf2b<<<dim3((D_ * D_) / 1024), cb, 0, stream>>>(Wk, Wall + (size_t)D_ * D_, D_ * D_);
  castf2b<<<dim3((D_ * D_) / 1024), cb, 0, stream>>>(Wv, Wall + (size_t)2 * D_ * D_, D_ * D_);
  castf2b<<<dim3((D_ * D_) / 1024), cb, 0, stream>>>(Wa, WaB, D_ * D_);
  castf2b<<<dim3((D_ * D_) / 1024), cb, 0, stream>>>(Wout, WoutB, D_ * D_);
  splitf<<<dim3((C_ * D_) / 1024), cb, 0, stream>>>(Wr, WrPh, WrPl, C_ * D_);
  wqk_t<<<dim3(64, 64), cb, 0, stream>>>(Wq, Wk, Wqkh, Wqkl);
  ln_kernel<<<dim3(T_), cb, 0, stream>>>(x, gamma, beta, hbuf, hlbuf);

  // M = Wr @ (Wq + 0.1 Wk)  -- split-precision exact, fp32 out [64][2048]
  gemm4_bt<<<dim3(1, D_ / 64), cb, 0, stream>>>(WrPh, WrPl, Wqkh, Wqkl, D_, C_, Mf, D_);
  splitf<<<dim3((C_ * D_) / 1024), cb, 0, stream>>>(Mf, Mh, Ml, C_ * D_);
  // logits = h @ M^T  -- split-precision exact, fp32 out [T][64]
  gemm4_bt<<<dim3(T_ / 128, 1), cb, 0, stream>>>(hbuf, hlbuf, Mh, Ml, D_, T_, logits, C_);

  // fused q/k norms + v : 256x256 8-phase GEMM, 128KB dynamic LDS
  hipFuncSetAttribute((const void*)qkv8, hipFuncAttributeMaxDynamicSharedMemorySize, 131072);
  qkv8<<<dim3(T_ / 256, NALL / 256), 512, 131072, stream>>>(hbuf, Wall, mask, qn2, kn2, vbuf);

  reg_reduce<<<dim3(T_ / 256), cb, 0, stream>>>(qn2, kn2, racc);
  router_kernel<<<dim3(T_ / 4), cb, 0, stream>>>(logits, br, cid, wt, chden);
  scatter_kernel<<<dim3(B_, D_ / 256, NCH), cb, 0, stream>>>(vbuf, cid, wt, partial);
  chmean_kernel<<<dim3((B_ * C_ * D_) / 256), cb, 0, stream>>>(partial, chden, chmean);
  gemm_bt<2><<<dim3(2, 16), cb, 0, stream>>>(chmean, WaB, D_, choutb, nullptr, ba);
  gemm_bt<3><<<dim3(2, 16), cb, 0, stream>>>(choutb, WoutB, D_, nullptr, chproj, nullptr);
  finalize_kernel<<<dim3(T_), cb, 0, stream>>>(x, bout, chproj, cid, wt, racc, out);
}